// Round 14
// baseline (123.035 us; speedup 1.0000x reference)
//
#include <hip/hip_runtime.h>

// NSLayer: per 8x8 matrix x: A = I - x x^T (symmetric),
// out = ((1+w7) I + w0 A + ... + w6 A^7) x  =  M x,
// M by matrix Horner: P = w6 A + w5 I; P <- P A + wk I (x6, wk ends 1+w7).
//
// R20 = R19's coalesced DMA/LDS shell + R6/R8's lane-split matrix Horner.
// Why: fp32 v_pk_fma issues over 4 cyc (157 TF spec = scalar rate; packing
// halves instructions, NOT cycles) -> R12-R19's packed power iteration
// never cut the VALU floor (7 steps x 576 cyc = 4032/wave). The R8-proven
// symmetric-product Horner costs 6 x ~352 + 512 matvec ~= 2624 cyc (-35%).
// fillBuffer saturates HBM at "9% occupancy" -> the derived occupancy
// metric is a red herring on gfx950; stop chasing it.
//
// Frame (R6/R8 proven): 2 lanes/matrix, lane h owns cols 4h..4h+3; rows
// half-permuted: p<4 -> 4h+p, p>=4 -> 4(1-h)+(p-4). Partner transfer for
// any symmetric entry: pswap at (p^4, q^4). Horner split: compile-time set
// T = {q<4} u {p+4<=q} (20 entries computed, 16 received via DPP).
// Shell (R19 proven): global_load_lds w=16 -> linear LDS, pre-swizzled
// source s(C)=C^(((C>>4)&3)<<1); frag chunk = l*16 + rr*2 + h (rr =
// permuted row), swizzle ^((l&3)<<1) -> 8-way bank spread all phases;
// contiguous 1KB drain.  y freed after Gram, re-read from LDS before the
// final matvec -> Horner live state ~ A+P+Q ~ 110-120 VGPR (R11 demotion
// guard). Health: WRITE ~65.5MB / FETCH ~33MB; ballooning = demotion.
//
// History: scattered I/O = 2 TB/s wall (R8-R13); coalesced shell ~39.5us
// (R14/R19); reg-prefetch spills (R16/R17); dbuf no help (R18).

typedef float v2f __attribute__((ext_vector_type(2)));

__device__ __forceinline__ v2f pk_mul(v2f a, v2f b) {
    v2f d;
    asm("v_pk_mul_f32 %0, %1, %2" : "=v"(d) : "v"(a), "v"(b));
    return d;
}
__device__ __forceinline__ void pk_fma(v2f &acc, v2f a, v2f b) {
    asm("v_pk_fma_f32 %0, %1, %2, %0" : "+v"(acc) : "v"(a), "v"(b));
}

// lane^1 partner swap as DPP quad_perm [1,0,3,2] (ctrl 0xB1), proven R10.
__device__ __forceinline__ float pswap(float x)
{
    return __builtin_bit_cast(float,
        __builtin_amdgcn_update_dpp(0, __builtin_bit_cast(int, x),
                                    0xB1, 0xF, 0xF, true));
}

// async DMA: 16B per lane, LDS dest = uniform base + lane*16 (linear).
#define GLOAD_LDS16(gp, lp)                                               \
    __builtin_amdgcn_global_load_lds(                                     \
        (const __attribute__((address_space(1))) void*)(gp),              \
        (__attribute__((address_space(3))) void*)(lp), 16, 0, 0)

#define SE(p, q) S[(p) < (q) ? (p) : (q)][(p) < (q) ? (q) : (p)]
#define AE(p, q) A[(p) < (q) ? (p) : (q)][(p) < (q) ? (q) : (p)]
#define UT(M, p, q) M[(p) < (q) ? (p) : (q)][(p) < (q) ? (q) : (p)]
#define IN_T(p, q) ((q) < 4 || (p) + 4 <= (q))

// One Horner step: Pn = Po * A + wk * I (symmetric, upper triangle only).
// 20 entries computed locally, 16 received from partner lane via DPP.
// Proven correct on HW in R8 (shfl) / R10 (pswap).
#define MAT_STEP(Pn, Po, wk)                                              \
    {                                                                     \
        _Pragma("unroll")                                                 \
        for (int p = 0; p < 8; ++p) {                                     \
            _Pragma("unroll")                                             \
            for (int q = p; q < 8; ++q) {                                 \
                if (IN_T(p, q)) {                                         \
                    float s = (p == q) ? (wk) : 0.0f;                     \
                    _Pragma("unroll")                                     \
                    for (int r = 0; r < 8; ++r)                           \
                        s += UT(Po, p, r) * AE(r, q);                     \
                    Pn[p][q] = s;                                         \
                }                                                         \
            }                                                             \
        }                                                                 \
        _Pragma("unroll")                                                 \
        for (int p = 0; p < 8; ++p) {                                     \
            _Pragma("unroll")                                             \
            for (int q = p; q < 8; ++q) {                                 \
                if (!IN_T(p, q)) {                                        \
                    const int pa = (p) ^ 4, pb = (q) ^ 4;                 \
                    const int lo = pa < pb ? pa : pb;                     \
                    const int hi = pa < pb ? pb : pa;                     \
                    Pn[p][q] = pswap(Pn[lo][hi]);                         \
                }                                                         \
            }                                                             \
        }                                                                 \
    }

__global__ __launch_bounds__(256, 2)
void ns_poly_kernel(const float* __restrict__ in,
                    const float* __restrict__ wp,
                    float* __restrict__ out)
{
    __shared__ float4 lds[2048];                      // 32 KB: 4 waves x 8 KB

    const int tid  = threadIdx.x;
    const int wave = tid >> 6;
    const int lane = tid & 63;
    const int l    = lane >> 1;                       // matrix-in-wave 0..31
    const int h    = lane & 1;                        // column-half owner

    const float w0 = wp[0], w1 = wp[1], w2 = wp[2], w3 = wp[3];
    const float w4 = wp[4], w5 = wp[5], w6 = wp[6], w7 = wp[7];

    float4* L = lds + wave * 512;                     // wave-private 8 KB

    const size_t base =
        ((size_t)blockIdx.x * 128 + (size_t)wave * 32) * 16;
    const float4* __restrict__ gin  = reinterpret_cast<const float4*>(in);
    float4*       __restrict__ gout = reinterpret_cast<float4*>(out);

    // ---- DMA stage: pre-swizzled global source -> linear LDS (R19) ----
#pragma unroll
    for (int it = 0; it < 8; ++it) {
        const int C = it * 64 + lane;
        const int Cs = C ^ (((C >> 4) & 3) << 1);
        GLOAD_LDS16(gin + base + Cs, L + it * 64);
    }
    asm volatile("s_waitcnt vmcnt(0)" ::: "memory");
    __builtin_amdgcn_sched_barrier(0);

    // ---- fragment read into the HALF-PERMUTED frame ----
    // slot p <- global row rr(p,h): p<4 -> 4h+p, p>=4 -> 4(1-h)+(p-4)
    v2f y[2][8];
#pragma unroll
    for (int p = 0; p < 8; ++p) {
        const int rr = (p < 4) ? (4 * h + p) : (4 * (1 - h) + (p - 4));
        const int f4 = (l * 16 + rr * 2 + h) ^ ((l & 3) << 1);
        const float4 v = L[f4];
        y[0][p] = (v2f){v.x, v.y};
        y[1][p] = (v2f){v.z, v.w};
    }

    // ---- partial Gram over my 4 columns (upper triangle, packed) ----
    float S[8][8];
#pragma unroll
    for (int p = 0; p < 8; ++p)
#pragma unroll
        for (int q = p; q < 8; ++q) {
            v2f a = pk_mul(y[0][p], y[0][q]);
            pk_fma(a, y[1][p], y[1][q]);
            S[p][q] = a.x + a.y;
        }
    // y dead here (re-read from LDS before matvec) -> low pressure in Horner

    // ---- A = I - S - partner(S): permuted frame, pswap at (p^4,q^4) ----
    float A[8][8];
#pragma unroll
    for (int p = 0; p < 8; ++p)
#pragma unroll
        for (int q = p; q < 8; ++q) {
            const float other = pswap(SE((p) ^ 4, (q) ^ 4));
            A[p][q] = (p == q ? 1.0f : 0.0f) - S[p][q] - other;
        }

    // ---- matrix Horner on the upper triangle (R8 proven) ----
    float P[8][8], Q[8][8];
#pragma unroll
    for (int p = 0; p < 8; ++p)
#pragma unroll
        for (int q = p; q < 8; ++q)
            P[p][q] = (p == q) ? fmaf(w6, A[p][q], w5) : w6 * A[p][q];

    MAT_STEP(Q, P, w4);           // w6 A^2 + w5 A + w4 I
    MAT_STEP(P, Q, w3);
    MAT_STEP(Q, P, w2);
    MAT_STEP(P, Q, w1);
    MAT_STEP(Q, P, w0);           // R = w6 A^6 + ... + w0 I
    MAT_STEP(P, Q, 1.0f + w7);    // M = R A + (1+w7) I   (final in P)

    // ---- re-read x fragments from LDS (input still resident) ----
    v2f z[2][8];
#pragma unroll
    for (int p = 0; p < 8; ++p) {
        const int rr = (p < 4) ? (4 * h + p) : (4 * (1 - h) + (p - 4));
        const int f4 = (l * 16 + rr * 2 + h) ^ ((l & 3) << 1);
        const float4 v = L[f4];
        z[0][p] = (v2f){v.x, v.y};
        z[1][p] = (v2f){v.z, v.w};
    }

    // ---- final matvec: t[jj][p] = sum_q M[p][q] x[q][col jj] (scalar) ----
    float t[4][8];
#pragma unroll
    for (int jj = 0; jj < 4; ++jj)
#pragma unroll
        for (int p = 0; p < 8; ++p) {
            float s = UT(P, p, 0) * z[jj >> 1][0][jj & 1];
#pragma unroll
            for (int q = 1; q < 8; ++q)
                s += UT(P, p, q) * z[jj >> 1][q][jj & 1];
            t[jj][p] = s;
        }

    // ---- fragment write back to LDS (permuted rows, swizzled) ----
#pragma unroll
    for (int p = 0; p < 8; ++p) {
        const int rr = (p < 4) ? (4 * h + p) : (4 * (1 - h) + (p - 4));
        const int f4 = (l * 16 + rr * 2 + h) ^ ((l & 3) << 1);
        L[f4] = make_float4(t[0][p], t[1][p], t[2][p], t[3][p]);
    }
    asm volatile("s_waitcnt lgkmcnt(0)" ::: "memory");

    // ---- drain: LDS -> contiguous global stores (R19) ----
#pragma unroll
    for (int it = 0; it < 8; ++it) {
        const int C = it * 64 + lane;
        gout[base + C] = L[C ^ (((C >> 4) & 3) << 1)];
    }
}

extern "C" void kernel_launch(void* const* d_in, const int* in_sizes, int n_in,
                              void* d_out, int out_size, void* d_ws, size_t ws_size,
                              hipStream_t stream)
{
    const float* in = (const float*)d_in[0];
    const float* w  = (const float*)d_in[1];
    float* outp     = (float*)d_out;

    const int nmat   = in_sizes[0] / 64;   // 262144 matrices
    const int blocks = nmat / 128;         // 2048 blocks, 128 matrices each
    ns_poly_kernel<<<blocks, 256, 0, stream>>>(in, w, outp);
}

// Round 16
// 121.036 us; speedup vs baseline: 1.0165x; 1.0165x over previous
//
#include <hip/hip_runtime.h>

// NSLayer: per 8x8 matrix x: A = I - x x^T (symmetric),
// out = (1+w7) x + sum_{k=1..7} w_{k-1} A^k x.
//
// R22 = R21 resubmitted verbatim: the R21 run died to the infra error
// "container failed twice" (same as R6/R15, both of which passed on
// resubmission). Math re-audited: col ownership, swizzle involution,
// quad butterfly, b64 bank floor, LDS bounds — all check out.
//
// R21: 4 lanes per matrix (halve wave span, double wave count).
// Diagnosis recap: memory floor ~15.5us, R19 VALU-busy ~16us, wall ~39.5us;
// VALUBusy ~40% even with prefetched data (R18) -> within-wave dependency
// stalls dominate; attribute-level residency levers all null (R13/R17/R19).
// R20 (scalar Horner) REGRESSED: VALU-busy 16.6->26us, VGPR pinned at 128.
// This round keeps R19's total VALU cycles but halves the serial span per
// wave and doubles wave count: more interleaving material for the HW
// scheduler without touching the proven math.
//
// Decomposition: lane = (l, j); matrix l = lane>>2 (16/wave), col-pair
// j = lane&3 owns cols {2j, 2j+1}. Natural row frame (no half-permute).
// Gram: per-lane partial over 2 cols, then quad butterfly:
//   full = r + dpp(lane^2, r),  r = S + dpp(lane^1, S)
// (quad_perm 0xB1 = [1,0,3,2], 0x4E = [2,3,0,1]). A = I - full.
// Power phase per lane: y = 1 col-pair slab; 72 pk/step (vs R19's 144).
//
// Shell (R19 proven): global_load_lds w=16 -> linear LDS, pre-swizzled
// source s(C)=C^(((C>>4)&3)<<1); 4 chunks/wave-iter (4KB/wave, 16KB/block);
// frag access = ds_read/write_b64 at chunk l*16+g*2+(j>>1), half (j&1) —
// each quad touches a contiguous 32B run -> b64 bank floor, conflict-free.
// Contiguous 1KB drain. Health: WRITE ~65.5MB / FETCH ~33MB (spill check),
// VGPR ~110-125, LDS 16384.
// History: scattered I/O = 2TB/s wall (R8-R13); coalesced shell ~39.5us
// (R14/R19); reg-prefetch spills (R16/R17); dbuf no help (R18); scalar
// Horner regresses under pressure (R20).

typedef float v2f __attribute__((ext_vector_type(2)));

// ---- packed fp32 primitives (encodings proven R11/R12/R14) ----
__device__ __forceinline__ v2f pk_mul(v2f a, v2f b) {
    v2f d;
    asm("v_pk_mul_f32 %0, %1, %2" : "=v"(d) : "v"(a), "v"(b));
    return d;
}
__device__ __forceinline__ void pk_fma(v2f &acc, v2f a, v2f b) {
    asm("v_pk_fma_f32 %0, %1, %2, %0" : "+v"(acc) : "v"(a), "v"(b));
}
__device__ __forceinline__ v2f pk_mul_lo(v2f a, v2f b) {
    v2f d;
    asm("v_pk_mul_f32 %0, %1, %2 op_sel:[0,0] op_sel_hi:[0,1]"
        : "=v"(d) : "v"(a), "v"(b));
    return d;
}
__device__ __forceinline__ void pk_fma_lo(v2f &acc, v2f a, v2f b) {
    asm("v_pk_fma_f32 %0, %1, %2, %0 op_sel:[0,0,0] op_sel_hi:[0,1,1]"
        : "+v"(acc) : "v"(a), "v"(b));
}
__device__ __forceinline__ void pk_fma_hi(v2f &acc, v2f a, v2f b) {
    asm("v_pk_fma_f32 %0, %1, %2, %0 op_sel:[1,0,0] op_sel_hi:[1,1,1]"
        : "+v"(acc) : "v"(a), "v"(b));
}

// quad_perm DPP swaps (proven encoding family, R10): lane^1 and lane^2.
__device__ __forceinline__ float qswap1(float x)   // [1,0,3,2] = 0xB1
{
    return __builtin_bit_cast(float,
        __builtin_amdgcn_update_dpp(0, __builtin_bit_cast(int, x),
                                    0xB1, 0xF, 0xF, true));
}
__device__ __forceinline__ float qswap2(float x)   // [2,3,0,1] = 0x4E
{
    return __builtin_bit_cast(float,
        __builtin_amdgcn_update_dpp(0, __builtin_bit_cast(int, x),
                                    0x4E, 0xF, 0xF, true));
}

// async DMA: 16B per lane, LDS dest = uniform base + lane*16 (linear).
#define GLOAD_LDS16(gp, lp)                                               \
    __builtin_amdgcn_global_load_lds(                                     \
        (const __attribute__((address_space(1))) void*)(gp),              \
        (__attribute__((address_space(3))) void*)(lp), 16, 0, 0)

#define AE(p, q) A[(p) < (q) ? (p) : (q)][(p) < (q) ? (q) : (p)]

// One power step on the lane's single col-pair slab: 72 pk instr.
#define POW_STEP(wk)                                                      \
    {                                                                     \
        const v2f wv = (v2f){(wk), (wk)};                                 \
        v2f n[8];                                                         \
        _Pragma("unroll")                                                 \
        for (int p = 0; p < 8; ++p) {                                     \
            v2f a = pk_mul_lo(Ar[p][0], y[0]);                            \
            pk_fma_hi(a, Ar[p][0], y[1]);                                 \
            pk_fma_lo(a, Ar[p][1], y[2]);                                 \
            pk_fma_hi(a, Ar[p][1], y[3]);                                 \
            pk_fma_lo(a, Ar[p][2], y[4]);                                 \
            pk_fma_hi(a, Ar[p][2], y[5]);                                 \
            pk_fma_lo(a, Ar[p][3], y[6]);                                 \
            pk_fma_hi(a, Ar[p][3], y[7]);                                 \
            n[p] = a;                                                     \
        }                                                                 \
        _Pragma("unroll")                                                 \
        for (int p = 0; p < 8; ++p) {                                     \
            y[p] = n[p];                                                  \
            pk_fma(acc[p], wv, n[p]);                                     \
        }                                                                 \
    }

__global__ __launch_bounds__(256, 2)
void ns_poly_kernel(const float* __restrict__ in,
                    const float* __restrict__ wp,
                    float* __restrict__ out)
{
    __shared__ float4 lds[1024];                      // 16 KB: 4 waves x 4 KB

    const int tid  = threadIdx.x;
    const int wave = tid >> 6;
    const int lane = tid & 63;
    const int l    = lane >> 2;                       // matrix-in-wave 0..15
    const int j    = lane & 3;                        // col-pair owner
    const int hj   = j >> 1;                          // chunk col-half
    const int bh   = j & 1;                           // b64 half within chunk

    const float w0 = wp[0], w1 = wp[1], w2 = wp[2], w3 = wp[3];
    const float w4 = wp[4], w5 = wp[5], w6 = wp[6], w7 = wp[7];

    float4* L  = lds + wave * 256;                    // wave-private 4 KB
    float2* L2 = reinterpret_cast<float2*>(L);

    // wave covers 16 matrices = 256 chunks (float4 units)
    const size_t base =
        ((size_t)blockIdx.x * 64 + (size_t)wave * 16) * 16;
    const float4* __restrict__ gin  = reinterpret_cast<const float4*>(in);
    float4*       __restrict__ gout = reinterpret_cast<float4*>(out);

    // ---- DMA stage: pre-swizzled global source -> linear LDS ----
#pragma unroll
    for (int it = 0; it < 4; ++it) {
        const int C  = it * 64 + lane;
        const int Cs = C ^ (((C >> 4) & 3) << 1);
        GLOAD_LDS16(gin + base + Cs, L + it * 64);
    }
    asm volatile("s_waitcnt vmcnt(0)" ::: "memory");
    __builtin_amdgcn_sched_barrier(0);

    // ---- fragment read: my col-pair, rows g=0..7 (ds_read_b64) ----
    v2f y[8];
#pragma unroll
    for (int g = 0; g < 8; ++g) {
        const int idx2 = (((l * 16 + g * 2 + hj) ^ ((l & 3) << 1)) << 1) | bh;
        const float2 v = L2[idx2];
        y[g] = (v2f){v.x, v.y};
    }

    // ---- partial Gram over my 2 columns (upper triangle) ----
    float S[8][8];
#pragma unroll
    for (int p = 0; p < 8; ++p)
#pragma unroll
        for (int q = p; q < 8; ++q) {
            const v2f a = pk_mul(y[p], y[q]);
            S[p][q] = a.x + a.y;
        }

    // ---- A = I - (quad-sum of S): two DPP butterflies ----
    float A[8][8];
#pragma unroll
    for (int p = 0; p < 8; ++p)
#pragma unroll
        for (int q = p; q < 8; ++q) {
            const float r    = S[p][q] + qswap1(S[p][q]);
            const float full = r + qswap2(r);
            A[p][q] = (p == q ? 1.0f : 0.0f) - full;
        }

    // ---- pack A rows into q-pairs for op_sel broadcast ----
    v2f Ar[8][4];
#pragma unroll
    for (int p = 0; p < 8; ++p)
#pragma unroll
        for (int jq = 0; jq < 4; ++jq)
            Ar[p][jq] = (v2f){AE(p, 2 * jq), AE(p, 2 * jq + 1)};

    // ---- power iteration: acc = (1+w7) x; 7x { y <- A y; acc += wk y } ----
    v2f acc[8];
    const v2f w7v = (v2f){1.0f + w7, 1.0f + w7};
#pragma unroll
    for (int p = 0; p < 8; ++p)
        acc[p] = pk_mul(w7v, y[p]);

    POW_STEP(w0);
    POW_STEP(w1);
    POW_STEP(w2);
    POW_STEP(w3);
    POW_STEP(w4);
    POW_STEP(w5);
    POW_STEP(w6);

    // ---- fragment write back (ds_write_b64, same conflict-free map) ----
#pragma unroll
    for (int g = 0; g < 8; ++g) {
        const int idx2 = (((l * 16 + g * 2 + hj) ^ ((l & 3) << 1)) << 1) | bh;
        L2[idx2] = make_float2(acc[g].x, acc[g].y);
    }
    asm volatile("s_waitcnt lgkmcnt(0)" ::: "memory");

    // ---- drain: LDS -> contiguous global stores ----
#pragma unroll
    for (int it = 0; it < 4; ++it) {
        const int C = it * 64 + lane;
        gout[base + C] = L[C ^ (((C >> 4) & 3) << 1)];
    }
}

extern "C" void kernel_launch(void* const* d_in, const int* in_sizes, int n_in,
                              void* d_out, int out_size, void* d_ws, size_t ws_size,
                              hipStream_t stream)
{
    const float* in = (const float*)d_in[0];
    const float* w  = (const float*)d_in[1];
    float* outp     = (float*)d_out;

    const int nmat   = in_sizes[0] / 64;   // 262144 matrices
    const int blocks = nmat / 64;          // 4096 blocks, 64 matrices each
    ns_poly_kernel<<<blocks, 256, 0, stream>>>(in, w, outp);
}